// Round 10
// baseline (423.756 us; speedup 1.0000x reference)
//
#include <hip/hip_runtime.h>

// Inputs fp32, OUTPUT fp32. N from in_sizes[3].
// ws layout: [0..255]   latent accumulator, 16 slots strided 16 floats (64 B apart)
//            [256..284] Tall (T(4), Tu(1), Tux(4), Tuxx(4), Tp(16) row-major)
//            [512]      (uint) phaseA block-done counter
//
// R10: consolidation. R9 chain-split = null (3rd exonerated lever after occupancy
//      R6-cfg and row-ILP R7); phaseC ~120us is this structure's measured ceiling.
//      MFMA rewrite excluded: bf16 error estimate ~0.5-1e-2 vs 9.45e-3 threshold +
//      blind fragment-layout risk (R3/R8 lesson).
//  - zero_kernel -> hipMemsetAsync (graph-legal; harness uses memsets itself).
//  - tnet folded into phaseA's LAST block (done-counter, agent-scope atomics;
//    kernel boundary orders Tall for phaseC). 4 dispatches -> 2.
//  - phaseC: R9 chain-split form (>= neutral, warm dispatches 114us).
//  - Tripwires: absmax stays 1.95e-3 (latent/tnet correctness); phaseC WRITE_SIZE
//    = 62500 KB; phaseA within +5us of 42us (LDS +1.7KB must not drop occupancy).
#define TPB 256

typedef unsigned int uint;
typedef float v2f __attribute__((ext_vector_type(2)));

__device__ __forceinline__ v2f pk_fma(v2f a, v2f b, v2f c) {
  return __builtin_elementwise_fma(a, b, c);
}

__device__ __forceinline__ float fast_tanh(float x) {
  // tanh(x) = 1 - 2/(1 + e^{2x}); e^{2x} = exp2(2*log2(e)*x)
  const float t = __builtin_amdgcn_exp2f(2.8853900817779268f * x);
  const float r = __builtin_amdgcn_rcpf(1.0f + t);
  return fmaf(-2.0f, r, 1.0f);
}

struct CArgs {
  const float* w1[5]; const float* b1[5];
  const float* w2[5]; const float* b2[5];
  const float* w3[5]; const float* b3[5];
};

// ---------- phase A: TWO rows/thread MLP 17->16->32->16, LDS write + block reduce,
// ----------          last block computes the 5 t-nets into ws Tall ----------
__global__ __launch_bounds__(TPB, 4) void phaseA_kernel(
    const float* __restrict__ means, const float* __restrict__ cov,
    const float* __restrict__ uu,    const float* __restrict__ bnd,
    const float* __restrict__ su,    const float* __restrict__ sux,
    const float* __restrict__ suxx,  const float* __restrict__ spde,
    const float* __restrict__ lw1, const float* __restrict__ lb1,
    const float* __restrict__ lw2, const float* __restrict__ lb2,
    const float* __restrict__ lw3, const float* __restrict__ lb3,
    CArgs ta, float* __restrict__ ws, int n) {
  const int tid = threadIdx.x;
  const int r0i = blockIdx.x * (TPB * 2) + tid;
  const int r1i = r0i + TPB;
  const bool v0 = r0i < n, v1 = r1i < n;
  const int r0 = v0 ? r0i : 0, r1 = v1 ? r1i : 0;
  __shared__ float red[TPB * 17];
  __shared__ float red2[16 * 17];

  // params = concat([means(2), cov(4), u(1), b(1), su(1), sux(2), suxx(2), spde(4)])
  auto load17 = [&](int r, float* x) {
    { const float2 v = *(const float2*)(means + (size_t)r * 2); x[0] = v.x; x[1] = v.y; }
    { const float4 v = *(const float4*)(cov   + (size_t)r * 4); x[2] = v.x; x[3] = v.y; x[4] = v.z; x[5] = v.w; }
    x[6] = uu[r]; x[7] = bnd[r]; x[8] = su[r];
    { const float2 v = *(const float2*)(sux   + (size_t)r * 2); x[9]  = v.x; x[10] = v.y; }
    { const float2 v = *(const float2*)(suxx  + (size_t)r * 2); x[11] = v.x; x[12] = v.y; }
    { const float4 v = *(const float4*)(spde  + (size_t)r * 4); x[13] = v.x; x[14] = v.y; x[15] = v.z; x[16] = v.w; }
  };
  float x0[17], x1[17];
  load17(r0, x0);
  load17(r1, x1);

  // L1: 17 -> 16 (K odd: scalar fmaf, each weight used for BOTH rows)
  v2f h1v0[8], h1v1[8];
#pragma unroll
  for (int o = 0; o < 16; o++) {
    float s0 = lb1[o], s1 = s0;
#pragma unroll
    for (int i = 0; i < 17; i++) {
      const float w = lw1[o * 17 + i];
      s0 = fmaf(w, x0[i], s0);
      s1 = fmaf(w, x1[i], s1);
    }
    h1v0[o >> 1][o & 1] = fast_tanh(s0);
    h1v1[o >> 1][o & 1] = fast_tanh(s1);
  }
  // L2: 16 -> 32, K-packed; each weight s-pair feeds both rows' pk chains
  v2f h2v0[16], h2v1[16];
#pragma unroll
  for (int o = 0; o < 32; o++) {
    v2f a0 = {lb2[o], 0.0f};
    v2f a1 = a0;
    const v2f* w2 = (const v2f*)(lw2 + o * 16);
#pragma unroll
    for (int m = 0; m < 8; m++) {
      const v2f w = w2[m];
      a0 = pk_fma(w, h1v0[m], a0);
      a1 = pk_fma(w, h1v1[m], a1);
    }
    h2v0[o >> 1][o & 1] = fast_tanh(a0.x + a0.y);
    h2v1[o >> 1][o & 1] = fast_tanh(a1.x + a1.y);
  }
  // L3: 32 -> 16, K-packed; per-thread sum of the two rows -> LDS (stride 17)
#pragma unroll
  for (int o = 0; o < 16; o++) {
    v2f a0 = {lb3[o], 0.0f};
    v2f a1 = a0;
    const v2f* w3 = (const v2f*)(lw3 + o * 32);
#pragma unroll
    for (int m = 0; m < 16; m++) {
      const v2f w = w3[m];
      a0 = pk_fma(w, h2v0[m], a0);
      a1 = pk_fma(w, h2v1[m], a1);
    }
    const float t0 = fast_tanh(a0.x + a0.y);
    const float t1 = fast_tanh(a1.x + a1.y);
    red[tid * 17 + o] = (v0 ? t0 : 0.0f) + (v1 ? t1 : 0.0f);
  }
  __syncthreads();

  // stage 2: thread (g = tid>>4, c = tid&15) sums 16 rows of column c
  {
    const int c = tid & 15, g = tid >> 4;
    float part = 0.0f;
#pragma unroll
    for (int rr = 0; rr < 16; rr++) part += red[(g * 16 + rr) * 17 + c];
    red2[g * 17 + c] = part;
  }
  __syncthreads();
  if (tid < 16) {
    float s = 0.0f;
#pragma unroll
    for (int g = 0; g < 16; g++) s += red2[g * 17 + tid];
    atomicAdd(&ws[tid * 16], s);  // 64 B apart: one cache line per component
  }

  // ---- last-block-done: the final block computes the 5 t-nets -> ws Tall ----
  __shared__ int amLast;
  if (tid == 0) {
    __threadfence();  // make this block's atomicAdds visible before the count
    uint* ctr = (uint*)ws + 512;
    const uint old = __hip_atomic_fetch_add(ctr, 1u, __ATOMIC_ACQ_REL,
                                            __HIP_MEMORY_SCOPE_AGENT);
    amLast = (old == (uint)gridDim.x - 1u);
  }
  __syncthreads();
  if (!amLast) return;

  // t-nets (this block only): latent -> Tall[29]
  __shared__ float lat[16];
  __shared__ float H1s[5][48];
  __shared__ float H2s[5][32];
  float* tall = ws + 256;

  if (tid < 16)
    lat[tid] = __hip_atomic_load(&ws[tid * 16], __ATOMIC_RELAXED,
                                 __HIP_MEMORY_SCOPE_AGENT) * (1.0f / (float)n);
  __syncthreads();
  if (tid < 240) {  // _tnet layer 1: 16 -> 48, tanh
    int net = tid / 48, o = tid % 48;
    float s = ta.b1[net][o];
#pragma unroll
    for (int i = 0; i < 16; i++) s = fmaf(ta.w1[net][o * 16 + i], lat[i], s);
    H1s[net][o] = fast_tanh(s);
  }
  __syncthreads();
  if (tid < 160) {  // _tnet layer 2: 48 -> 32, tanh
    int net = tid / 32, o = tid % 32;
    float s = ta.b2[net][o];
#pragma unroll
    for (int i = 0; i < 48; i++) s = fmaf(ta.w2[net][o * 48 + i], H1s[net][i], s);
    H2s[net][o] = fast_tanh(s);
  }
  __syncthreads();
  if (tid < 29) {   // _tnet layer 3: 32 -> dd*dd, + eye(dd)
    int net, o, dd;
    if      (tid < 4)  { net = 0; o = tid;      dd = 2; }
    else if (tid < 5)  { net = 1; o = tid - 4;  dd = 1; }
    else if (tid < 9)  { net = 2; o = tid - 5;  dd = 2; }
    else if (tid < 13) { net = 3; o = tid - 9;  dd = 2; }
    else               { net = 4; o = tid - 13; dd = 4; }
    float s = ta.b3[net][o];
#pragma unroll
    for (int i = 0; i < 32; i++) s = fmaf(ta.w3[net][o * 32 + i], H2s[net][i], s);
    if (o / dd == o % dd) s += 1.0f;
    tall[tid] = s;  // visible to phaseC at kernel boundary
  }
}

// ---------- phase C: ONE row/thread, streaming transform + j-net, chain-split ----------
__global__ __launch_bounds__(TPB, 4) void phaseC_kernel(
    const float* __restrict__ tall,
    const float* __restrict__ cov,  const float* __restrict__ uu,
    const float* __restrict__ bnd,  const float* __restrict__ su,
    const float* __restrict__ sux,  const float* __restrict__ suxx,
    const float* __restrict__ spde,
    const float* __restrict__ jw1,  const float* __restrict__ jb1,
    const float* __restrict__ jw2,  const float* __restrict__ jb2,
    const float* __restrict__ jw3,  const float* __restrict__ jb3,
    const float* __restrict__ jw4,  const float* __restrict__ jb4,
    float* __restrict__ out, int n) {
  const int row = blockIdx.x * TPB + threadIdx.x;
  if (row >= n) return;

  // Tall[29]: wave-uniform -> scalar loads through K$ (do NOT copy into a VGPR array)
  // T(4)@0, Tu(1)@4, Tux(4)@5, Tuxx(4)@9, Tp(16)@13 (row-major dd x dd)

  // ---- literal t_params ----
  const float4 c4 = *(const float4*)(cov + (size_t)row * 4);
  float tp[15];
  // t_cov[i,k] = sum_j T[i,j] * cov[j,k]
  tp[0] = tall[0] * c4.x + tall[1] * c4.z;
  tp[1] = tall[0] * c4.y + tall[1] * c4.w;
  tp[2] = tall[2] * c4.x + tall[3] * c4.z;
  tp[3] = tall[2] * c4.y + tall[3] * c4.w;
  tp[4] = tall[4] * uu[row];          // t_u
  tp[5] = bnd[row];                   // b passthrough
  tp[6] = tall[4] * su[row];          // t_su
  { const float2 v = *(const float2*)(sux + (size_t)row * 2);
    tp[7] = tall[5] * v.x + tall[6] * v.y;
    tp[8] = tall[7] * v.x + tall[8] * v.y; }
  { const float2 v = *(const float2*)(suxx + (size_t)row * 2);
    tp[9]  = tall[9]  * v.x + tall[10] * v.y;
    tp[10] = tall[11] * v.x + tall[12] * v.y; }
  { const float4 v = *(const float4*)(spde + (size_t)row * 4);
#pragma unroll
    for (int a = 0; a < 4; a++)
      tp[11 + a] = tall[13 + a * 4] * v.x + tall[13 + a * 4 + 1] * v.y +
                   tall[13 + a * 4 + 2] * v.z + tall[13 + a * 4 + 3] * v.w; }

  // ---- j-net: 15 -> 16 -> 32 -> 48 -> 16 ----
  // L1 (K=15 odd: scalar fmaf), results into v2f pairs
  v2f a1v[8];
#pragma unroll
  for (int o = 0; o < 16; o++) {
    float s = jb1[o];
#pragma unroll
    for (int i = 0; i < 15; i++) s = fmaf(jw1[o * 15 + i], tp[i], s);
    a1v[o >> 1][o & 1] = fast_tanh(s);
  }
  // L2: 16 -> 32, packed, chain-split (2 x 4-deep, merged by one packed add)
  v2f a2v[16];
#pragma unroll
  for (int o = 0; o < 32; o++) {
    v2f aA = {jb2[o], 0.0f};
    v2f aB = {0.0f, 0.0f};
    const v2f* w2 = (const v2f*)(jw2 + o * 16);
#pragma unroll
    for (int m = 0; m < 4; m++) {
      aA = pk_fma(w2[m],     a1v[m],     aA);
      aB = pk_fma(w2[m + 4], a1v[m + 4], aB);
    }
    const v2f aS = aA + aB;
    a2v[o >> 1][o & 1] = fast_tanh(aS.x + aS.y);
  }
  // L3+L4 streamed in o-PAIRS, L3 chain-split (4 chains x 8-deep per pair).
  // Never materializes g3[48]; peak live = a2v(32) + a4v(32) + 8 acc regs.
  v2f a4v[16];
#pragma unroll
  for (int j = 0; j < 16; j++) { v2f t = {jb4[j], 0.0f}; a4v[j] = t; }
#pragma unroll 4
  for (int op = 0; op < 24; op++) {
    const int o0 = op * 2;
    v2f acc0a = {jb3[o0], 0.0f};
    v2f acc0b = {0.0f, 0.0f};
    v2f acc1a = {jb3[o0 + 1], 0.0f};
    v2f acc1b = {0.0f, 0.0f};
    const v2f* w30 = (const v2f*)(jw3 + o0 * 32);
    const v2f* w31 = (const v2f*)(jw3 + (o0 + 1) * 32);
#pragma unroll
    for (int m = 0; m < 8; m++) {
      acc0a = pk_fma(w30[m],     a2v[m],     acc0a);
      acc0b = pk_fma(w30[m + 8], a2v[m + 8], acc0b);
      acc1a = pk_fma(w31[m],     a2v[m],     acc1a);
      acc1b = pk_fma(w31[m + 8], a2v[m + 8], acc1b);
    }
    const v2f s0 = acc0a + acc0b;
    const v2f s1 = acc1a + acc1b;
    v2f h;
    h.x = fast_tanh(s0.x + s0.y);
    h.y = fast_tanh(s1.x + s1.y);
#pragma unroll
    for (int j = 0; j < 16; j++)
      a4v[j] = pk_fma(*(const v2f*)(jw4 + j * 48 + o0), h, a4v[j]);
  }
  float4* p = (float4*)(out + (size_t)row * 16);
  p[0] = make_float4(a4v[0].x + a4v[0].y,   a4v[1].x + a4v[1].y,
                     a4v[2].x + a4v[2].y,   a4v[3].x + a4v[3].y);
  p[1] = make_float4(a4v[4].x + a4v[4].y,   a4v[5].x + a4v[5].y,
                     a4v[6].x + a4v[6].y,   a4v[7].x + a4v[7].y);
  p[2] = make_float4(a4v[8].x + a4v[8].y,   a4v[9].x + a4v[9].y,
                     a4v[10].x + a4v[10].y, a4v[11].x + a4v[11].y);
  p[3] = make_float4(a4v[12].x + a4v[12].y, a4v[13].x + a4v[13].y,
                     a4v[14].x + a4v[14].y, a4v[15].x + a4v[15].y);
}

// ---------- launch ----------
extern "C" void kernel_launch(void* const* d_in, const int* in_sizes, int n_in,
                              void* d_out, int out_size, void* d_ws, size_t ws_size,
                              hipStream_t stream) {
  float* ws = (float*)d_ws;
  const int n = in_sizes[3];              // boundaries: (N,)
  const int nblkA = (n + 2 * TPB - 1) / (2 * TPB);
  const int nblkC = (n + TPB - 1) / TPB;

  // zero acc slots [0..255], Tall [256..284], done counter [512] in one memset
  hipMemsetAsync(d_ws, 0, 4096, stream);

  CArgs ca;
  for (int k = 0; k < 5; k++) {
    int b = 14 + 6 * k;
    ca.w1[k] = (const float*)d_in[b];     ca.b1[k] = (const float*)d_in[b + 1];
    ca.w2[k] = (const float*)d_in[b + 2]; ca.b2[k] = (const float*)d_in[b + 3];
    ca.w3[k] = (const float*)d_in[b + 4]; ca.b3[k] = (const float*)d_in[b + 5];
  }

  phaseA_kernel<<<nblkA, TPB, 0, stream>>>(
      (const float*)d_in[0], (const float*)d_in[1], (const float*)d_in[2],
      (const float*)d_in[3], (const float*)d_in[4], (const float*)d_in[5],
      (const float*)d_in[6], (const float*)d_in[7],
      (const float*)d_in[8], (const float*)d_in[9], (const float*)d_in[10],
      (const float*)d_in[11], (const float*)d_in[12], (const float*)d_in[13],
      ca, ws, n);

  phaseC_kernel<<<nblkC, TPB, 0, stream>>>(
      ws + 256,
      (const float*)d_in[1], (const float*)d_in[2], (const float*)d_in[3],
      (const float*)d_in[4], (const float*)d_in[5], (const float*)d_in[6],
      (const float*)d_in[7],
      (const float*)d_in[44], (const float*)d_in[45],
      (const float*)d_in[46], (const float*)d_in[47],
      (const float*)d_in[48], (const float*)d_in[49],
      (const float*)d_in[50], (const float*)d_in[51],
      (float*)d_out, n);
}

// Round 12
// 373.897 us; speedup vs baseline: 1.1334x; 1.1334x over previous
//
#include <hip/hip_runtime.h>

// Inputs fp32, OUTPUT fp32. N from in_sizes[3].
// ws layout: [0..255]   latent accumulator, 16 slots strided 16 floats (64 B apart)
//            [256..284] Tall (T(4), Tu(1), Tux(4), Tuxx(4), Tp(16) row-major)
//
// R12 = R11 resubmitted verbatim (R11 bench was an infra failure: container died,
// kernel never ran). Best-known composition:
//  - phaseA: R6 standalone 2-row/thread (scalar weight stream amortized over 2 rows).
//  - tnet: separate 1-block kernel (~5us).
//  - phaseC: R9 chain-split (warm dispatches 114us, fastest measured).
//  - zero_kernel -> hipMemsetAsync (proven correct in R10; one fewer dispatch).
//  - Totals R6/R7/R9 = 354/386/385 with IDENTICAL per-dispatch times -> harness gap
//    noise is +-30us; judge only per-dispatch counters.
//  - Pre-commit: if this reproduces ~354 and the counter picture is unchanged,
//    declare structural ceiling next round (phaseC: occupancy/row-ILP/dep-chain/
//    packing all exonerated; MFMA excluded on accuracy budget ~0.5-1e-2 vs 9.45e-3).
#define TPB 256

typedef unsigned int uint;
typedef float v2f __attribute__((ext_vector_type(2)));

__device__ __forceinline__ v2f pk_fma(v2f a, v2f b, v2f c) {
  return __builtin_elementwise_fma(a, b, c);
}

__device__ __forceinline__ float fast_tanh(float x) {
  // tanh(x) = 1 - 2/(1 + e^{2x}); e^{2x} = exp2(2*log2(e)*x)
  const float t = __builtin_amdgcn_exp2f(2.8853900817779268f * x);
  const float r = __builtin_amdgcn_rcpf(1.0f + t);
  return fmaf(-2.0f, r, 1.0f);
}

// ---------- phase A: TWO rows/thread MLP 17->16->32->16, LDS write + block reduce ----------
__global__ __launch_bounds__(TPB, 4) void phaseA_kernel(
    const float* __restrict__ means, const float* __restrict__ cov,
    const float* __restrict__ uu,    const float* __restrict__ bnd,
    const float* __restrict__ su,    const float* __restrict__ sux,
    const float* __restrict__ suxx,  const float* __restrict__ spde,
    const float* __restrict__ lw1, const float* __restrict__ lb1,
    const float* __restrict__ lw2, const float* __restrict__ lb2,
    const float* __restrict__ lw3, const float* __restrict__ lb3,
    float* __restrict__ acc_out, int n) {
  const int tid = threadIdx.x;
  const int r0i = blockIdx.x * (TPB * 2) + tid;
  const int r1i = r0i + TPB;
  const bool v0 = r0i < n, v1 = r1i < n;
  const int r0 = v0 ? r0i : 0, r1 = v1 ? r1i : 0;
  __shared__ float red[TPB * 17];
  __shared__ float red2[16 * 17];

  // params = concat([means(2), cov(4), u(1), b(1), su(1), sux(2), suxx(2), spde(4)])
  auto load17 = [&](int r, float* x) {
    { const float2 v = *(const float2*)(means + (size_t)r * 2); x[0] = v.x; x[1] = v.y; }
    { const float4 v = *(const float4*)(cov   + (size_t)r * 4); x[2] = v.x; x[3] = v.y; x[4] = v.z; x[5] = v.w; }
    x[6] = uu[r]; x[7] = bnd[r]; x[8] = su[r];
    { const float2 v = *(const float2*)(sux   + (size_t)r * 2); x[9]  = v.x; x[10] = v.y; }
    { const float2 v = *(const float2*)(suxx  + (size_t)r * 2); x[11] = v.x; x[12] = v.y; }
    { const float4 v = *(const float4*)(spde  + (size_t)r * 4); x[13] = v.x; x[14] = v.y; x[15] = v.z; x[16] = v.w; }
  };
  float x0[17], x1[17];
  load17(r0, x0);
  load17(r1, x1);

  // L1: 17 -> 16 (K odd: scalar fmaf, each weight used for BOTH rows)
  v2f h1v0[8], h1v1[8];
#pragma unroll
  for (int o = 0; o < 16; o++) {
    float s0 = lb1[o], s1 = s0;
#pragma unroll
    for (int i = 0; i < 17; i++) {
      const float w = lw1[o * 17 + i];
      s0 = fmaf(w, x0[i], s0);
      s1 = fmaf(w, x1[i], s1);
    }
    h1v0[o >> 1][o & 1] = fast_tanh(s0);
    h1v1[o >> 1][o & 1] = fast_tanh(s1);
  }
  // L2: 16 -> 32, K-packed; each weight s-pair feeds both rows' pk chains
  v2f h2v0[16], h2v1[16];
#pragma unroll
  for (int o = 0; o < 32; o++) {
    v2f a0 = {lb2[o], 0.0f};
    v2f a1 = a0;
    const v2f* w2 = (const v2f*)(lw2 + o * 16);
#pragma unroll
    for (int m = 0; m < 8; m++) {
      const v2f w = w2[m];
      a0 = pk_fma(w, h1v0[m], a0);
      a1 = pk_fma(w, h1v1[m], a1);
    }
    h2v0[o >> 1][o & 1] = fast_tanh(a0.x + a0.y);
    h2v1[o >> 1][o & 1] = fast_tanh(a1.x + a1.y);
  }
  // L3: 32 -> 16, K-packed; per-thread sum of the two rows -> LDS (stride 17)
#pragma unroll
  for (int o = 0; o < 16; o++) {
    v2f a0 = {lb3[o], 0.0f};
    v2f a1 = a0;
    const v2f* w3 = (const v2f*)(lw3 + o * 32);
#pragma unroll
    for (int m = 0; m < 16; m++) {
      const v2f w = w3[m];
      a0 = pk_fma(w, h2v0[m], a0);
      a1 = pk_fma(w, h2v1[m], a1);
    }
    const float t0 = fast_tanh(a0.x + a0.y);
    const float t1 = fast_tanh(a1.x + a1.y);
    red[tid * 17 + o] = (v0 ? t0 : 0.0f) + (v1 ? t1 : 0.0f);
  }
  __syncthreads();

  // stage 2: thread (g = tid>>4, c = tid&15) sums 16 rows of column c
  {
    const int c = tid & 15, g = tid >> 4;
    float part = 0.0f;
#pragma unroll
    for (int rr = 0; rr < 16; rr++) part += red[(g * 16 + rr) * 17 + c];
    red2[g * 17 + c] = part;
  }
  __syncthreads();
  if (tid < 16) {
    float s = 0.0f;
#pragma unroll
    for (int g = 0; g < 16; g++) s += red2[g * 17 + tid];
    atomicAdd(&acc_out[tid * 16], s);  // 64 B apart: one cache line per component
  }
}

// ---------- t-nets: single block, writes Tall[29] to ws ----------
struct CArgs {
  const float* w1[5]; const float* b1[5];
  const float* w2[5]; const float* b2[5];
  const float* w3[5]; const float* b3[5];
};

__global__ __launch_bounds__(256) void tnet_kernel(
    CArgs ta, const float* __restrict__ ws_acc, float* __restrict__ tall, int n) {
  const int tid = threadIdx.x;
  __shared__ float lat[16];
  __shared__ float H1s[5][48];
  __shared__ float H2s[5][32];

  if (tid < 16) lat[tid] = ws_acc[tid * 16] * (1.0f / (float)n);
  __syncthreads();
  if (tid < 240) {  // _tnet layer 1: 16 -> 48, tanh
    int net = tid / 48, o = tid % 48;
    float s = ta.b1[net][o];
#pragma unroll
    for (int i = 0; i < 16; i++) s = fmaf(ta.w1[net][o * 16 + i], lat[i], s);
    H1s[net][o] = fast_tanh(s);
  }
  __syncthreads();
  if (tid < 160) {  // _tnet layer 2: 48 -> 32, tanh
    int net = tid / 32, o = tid % 32;
    float s = ta.b2[net][o];
#pragma unroll
    for (int i = 0; i < 48; i++) s = fmaf(ta.w2[net][o * 48 + i], H1s[net][i], s);
    H2s[net][o] = fast_tanh(s);
  }
  __syncthreads();
  if (tid < 29) {   // _tnet layer 3: 32 -> dd*dd, + eye(dd)
    int net, o, dd;
    if      (tid < 4)  { net = 0; o = tid;      dd = 2; }
    else if (tid < 5)  { net = 1; o = tid - 4;  dd = 1; }
    else if (tid < 9)  { net = 2; o = tid - 5;  dd = 2; }
    else if (tid < 13) { net = 3; o = tid - 9;  dd = 2; }
    else               { net = 4; o = tid - 13; dd = 4; }
    float s = ta.b3[net][o];
#pragma unroll
    for (int i = 0; i < 32; i++) s = fmaf(ta.w3[net][o * 32 + i], H2s[net][i], s);
    if (o / dd == o % dd) s += 1.0f;
    tall[tid] = s;
  }
}

// ---------- phase C: ONE row/thread, streaming transform + j-net, chain-split ----------
__global__ __launch_bounds__(TPB, 4) void phaseC_kernel(
    const float* __restrict__ tall,
    const float* __restrict__ cov,  const float* __restrict__ uu,
    const float* __restrict__ bnd,  const float* __restrict__ su,
    const float* __restrict__ sux,  const float* __restrict__ suxx,
    const float* __restrict__ spde,
    const float* __restrict__ jw1,  const float* __restrict__ jb1,
    const float* __restrict__ jw2,  const float* __restrict__ jb2,
    const float* __restrict__ jw3,  const float* __restrict__ jb3,
    const float* __restrict__ jw4,  const float* __restrict__ jb4,
    float* __restrict__ out, int n) {
  const int row = blockIdx.x * TPB + threadIdx.x;
  if (row >= n) return;

  // Tall[29]: wave-uniform -> scalar loads through K$ (do NOT copy into a VGPR array)
  // T(4)@0, Tu(1)@4, Tux(4)@5, Tuxx(4)@9, Tp(16)@13 (row-major dd x dd)

  // ---- literal t_params ----
  const float4 c4 = *(const float4*)(cov + (size_t)row * 4);
  float tp[15];
  // t_cov[i,k] = sum_j T[i,j] * cov[j,k]
  tp[0] = tall[0] * c4.x + tall[1] * c4.z;
  tp[1] = tall[0] * c4.y + tall[1] * c4.w;
  tp[2] = tall[2] * c4.x + tall[3] * c4.z;
  tp[3] = tall[2] * c4.y + tall[3] * c4.w;
  tp[4] = tall[4] * uu[row];          // t_u
  tp[5] = bnd[row];                   // b passthrough
  tp[6] = tall[4] * su[row];          // t_su
  { const float2 v = *(const float2*)(sux + (size_t)row * 2);
    tp[7] = tall[5] * v.x + tall[6] * v.y;
    tp[8] = tall[7] * v.x + tall[8] * v.y; }
  { const float2 v = *(const float2*)(suxx + (size_t)row * 2);
    tp[9]  = tall[9]  * v.x + tall[10] * v.y;
    tp[10] = tall[11] * v.x + tall[12] * v.y; }
  { const float4 v = *(const float4*)(spde + (size_t)row * 4);
#pragma unroll
    for (int a = 0; a < 4; a++)
      tp[11 + a] = tall[13 + a * 4] * v.x + tall[13 + a * 4 + 1] * v.y +
                   tall[13 + a * 4 + 2] * v.z + tall[13 + a * 4 + 3] * v.w; }

  // ---- j-net: 15 -> 16 -> 32 -> 48 -> 16 ----
  // L1 (K=15 odd: scalar fmaf), results into v2f pairs
  v2f a1v[8];
#pragma unroll
  for (int o = 0; o < 16; o++) {
    float s = jb1[o];
#pragma unroll
    for (int i = 0; i < 15; i++) s = fmaf(jw1[o * 15 + i], tp[i], s);
    a1v[o >> 1][o & 1] = fast_tanh(s);
  }
  // L2: 16 -> 32, packed, chain-split (2 x 4-deep, merged by one packed add)
  v2f a2v[16];
#pragma unroll
  for (int o = 0; o < 32; o++) {
    v2f aA = {jb2[o], 0.0f};
    v2f aB = {0.0f, 0.0f};
    const v2f* w2 = (const v2f*)(jw2 + o * 16);
#pragma unroll
    for (int m = 0; m < 4; m++) {
      aA = pk_fma(w2[m],     a1v[m],     aA);
      aB = pk_fma(w2[m + 4], a1v[m + 4], aB);
    }
    const v2f aS = aA + aB;
    a2v[o >> 1][o & 1] = fast_tanh(aS.x + aS.y);
  }
  // L3+L4 streamed in o-PAIRS, L3 chain-split (4 chains x 8-deep per pair).
  // Never materializes g3[48]; peak live = a2v(32) + a4v(32) + 8 acc regs.
  v2f a4v[16];
#pragma unroll
  for (int j = 0; j < 16; j++) { v2f t = {jb4[j], 0.0f}; a4v[j] = t; }
#pragma unroll 4
  for (int op = 0; op < 24; op++) {
    const int o0 = op * 2;
    v2f acc0a = {jb3[o0], 0.0f};
    v2f acc0b = {0.0f, 0.0f};
    v2f acc1a = {jb3[o0 + 1], 0.0f};
    v2f acc1b = {0.0f, 0.0f};
    const v2f* w30 = (const v2f*)(jw3 + o0 * 32);
    const v2f* w31 = (const v2f*)(jw3 + (o0 + 1) * 32);
#pragma unroll
    for (int m = 0; m < 8; m++) {
      acc0a = pk_fma(w30[m],     a2v[m],     acc0a);
      acc0b = pk_fma(w30[m + 8], a2v[m + 8], acc0b);
      acc1a = pk_fma(w31[m],     a2v[m],     acc1a);
      acc1b = pk_fma(w31[m + 8], a2v[m + 8], acc1b);
    }
    const v2f s0 = acc0a + acc0b;
    const v2f s1 = acc1a + acc1b;
    v2f h;
    h.x = fast_tanh(s0.x + s0.y);
    h.y = fast_tanh(s1.x + s1.y);
#pragma unroll
    for (int j = 0; j < 16; j++)
      a4v[j] = pk_fma(*(const v2f*)(jw4 + j * 48 + o0), h, a4v[j]);
  }
  float4* p = (float4*)(out + (size_t)row * 16);
  p[0] = make_float4(a4v[0].x + a4v[0].y,   a4v[1].x + a4v[1].y,
                     a4v[2].x + a4v[2].y,   a4v[3].x + a4v[3].y);
  p[1] = make_float4(a4v[4].x + a4v[4].y,   a4v[5].x + a4v[5].y,
                     a4v[6].x + a4v[6].y,   a4v[7].x + a4v[7].y);
  p[2] = make_float4(a4v[8].x + a4v[8].y,   a4v[9].x + a4v[9].y,
                     a4v[10].x + a4v[10].y, a4v[11].x + a4v[11].y);
  p[3] = make_float4(a4v[12].x + a4v[12].y, a4v[13].x + a4v[13].y,
                     a4v[14].x + a4v[14].y, a4v[15].x + a4v[15].y);
}

// ---------- launch ----------
extern "C" void kernel_launch(void* const* d_in, const int* in_sizes, int n_in,
                              void* d_out, int out_size, void* d_ws, size_t ws_size,
                              hipStream_t stream) {
  float* ws = (float*)d_ws;
  const int n = in_sizes[3];              // boundaries: (N,)
  const int nblkA = (n + 2 * TPB - 1) / (2 * TPB);
  const int nblkC = (n + TPB - 1) / TPB;

  // zero acc slots [0..255] + Tall [256..284] (proven correct in R10)
  hipMemsetAsync(d_ws, 0, 2048, stream);

  phaseA_kernel<<<nblkA, TPB, 0, stream>>>(
      (const float*)d_in[0], (const float*)d_in[1], (const float*)d_in[2],
      (const float*)d_in[3], (const float*)d_in[4], (const float*)d_in[5],
      (const float*)d_in[6], (const float*)d_in[7],
      (const float*)d_in[8], (const float*)d_in[9], (const float*)d_in[10],
      (const float*)d_in[11], (const float*)d_in[12], (const float*)d_in[13],
      ws, n);

  CArgs ca;
  for (int k = 0; k < 5; k++) {
    int b = 14 + 6 * k;
    ca.w1[k] = (const float*)d_in[b];     ca.b1[k] = (const float*)d_in[b + 1];
    ca.w2[k] = (const float*)d_in[b + 2]; ca.b2[k] = (const float*)d_in[b + 3];
    ca.w3[k] = (const float*)d_in[b + 4]; ca.b3[k] = (const float*)d_in[b + 5];
  }

  tnet_kernel<<<1, 256, 0, stream>>>(ca, ws, ws + 256, n);

  phaseC_kernel<<<nblkC, TPB, 0, stream>>>(
      ws + 256,
      (const float*)d_in[1], (const float*)d_in[2], (const float*)d_in[3],
      (const float*)d_in[4], (const float*)d_in[5], (const float*)d_in[6],
      (const float*)d_in[7],
      (const float*)d_in[44], (const float*)d_in[45],
      (const float*)d_in[46], (const float*)d_in[47],
      (const float*)d_in[48], (const float*)d_in[49],
      (const float*)d_in[50], (const float*)d_in[51],
      (float*)d_out, n);
}